// Round 1
// baseline (3159.036 us; speedup 1.0000x reference)
//
#include <hip/hip_runtime.h>

// Problem dims (fixed by setup_inputs)
#define B_ROWS 2048
#define K_DIM  3072     // T*d_in = 4*768
#define N_DIM  16384    // d_sae
#define TOPK   128
#define XHAT_ELEMS (B_ROWS * K_DIM)   // 6291456

// ---------------------------------------------------------------------------
// Encoder GEMM: pre[M=2048, N=16384] = X[M,K=3072] * W[K,N] + b_enc
// fp32, 128x128 tile, TK=8, 256 threads, 8x8 microtile (split 4+4 layout).
// Output buffer (z-section of d_out) is only 4-byte aligned -> scalar stores.
// ---------------------------------------------------------------------------
__global__ __launch_bounds__(256) void enc_gemm(const float* __restrict__ X,
                                                const float* __restrict__ W,
                                                const float* __restrict__ benc,
                                                float* __restrict__ pre) {
    __shared__ float As[8][128];   // As[k][m]
    __shared__ float Bs[8][128];   // Bs[k][n]

    const int t  = threadIdx.x;
    const int bx = blockIdx.x;     // N tile (0..127)
    const int by = blockIdx.y;     // M tile (0..15)
    const int tx = t & 15;
    const int ty = t >> 4;

    // A tile load: 128x8 floats, one float4 per thread
    const int arow = t >> 1;            // 0..127
    const int acol = (t & 1) << 2;      // 0 or 4
    // B tile load: 8x128 floats, one float4 per thread
    const int brow = t >> 5;            // 0..7
    const int bcol = (t & 31) << 2;     // 0..124

    const float* Ap = X + (size_t)(by * 128 + arow) * K_DIM + acol;
    const float* Bp = W + (size_t)brow * N_DIM + bx * 128 + bcol;

    float acc[8][8];
#pragma unroll
    for (int i = 0; i < 8; ++i)
#pragma unroll
        for (int j = 0; j < 8; ++j) acc[i][j] = 0.f;

    float4 av = *(const float4*)Ap;
    float4 bv = *(const float4*)Bp;

    for (int k0 = 0; k0 < K_DIM; k0 += 8) {
        __syncthreads();
        As[acol + 0][arow] = av.x;
        As[acol + 1][arow] = av.y;
        As[acol + 2][arow] = av.z;
        As[acol + 3][arow] = av.w;
        *(float4*)&Bs[brow][bcol] = bv;
        __syncthreads();
        if (k0 + 8 < K_DIM) {
            av = *(const float4*)(Ap + k0 + 8);
            bv = *(const float4*)(Bp + (size_t)(k0 + 8) * N_DIM);
        }
#pragma unroll
        for (int kk = 0; kk < 8; ++kk) {
            float4 a0 = *(const float4*)&As[kk][ty * 4];
            float4 a1 = *(const float4*)&As[kk][64 + ty * 4];
            float4 b0 = *(const float4*)&Bs[kk][tx * 4];
            float4 b1 = *(const float4*)&Bs[kk][64 + tx * 4];
            float a[8] = {a0.x, a0.y, a0.z, a0.w, a1.x, a1.y, a1.z, a1.w};
            float b[8] = {b0.x, b0.y, b0.z, b0.w, b1.x, b1.y, b1.z, b1.w};
#pragma unroll
            for (int i = 0; i < 8; ++i)
#pragma unroll
                for (int j = 0; j < 8; ++j)
                    acc[i][j] = fmaf(a[i], b[j], acc[i][j]);
        }
    }

    // Epilogue: add b_enc, scalar stores (pre base only 4B-aligned)
    const int ccolbase = bx * 128;
    float bvals[8];
#pragma unroll
    for (int j = 0; j < 8; ++j) {
        int c = (j < 4) ? (tx * 4 + j) : (64 + tx * 4 + (j - 4));
        bvals[j] = benc[ccolbase + c];
    }
#pragma unroll
    for (int i = 0; i < 8; ++i) {
        int r = (i < 4) ? (ty * 4 + i) : (64 + ty * 4 + (i - 4));
        float* outp = pre + (size_t)(by * 128 + r) * N_DIM + ccolbase;
#pragma unroll
        for (int j = 0; j < 8; ++j) {
            int c = (j < 4) ? (tx * 4 + j) : (64 + tx * 4 + (j - 4));
            outp[c] = acc[i][j] + bvals[j];
        }
    }
}

// ---------------------------------------------------------------------------
// Top-k per row (in place: reads pre row, writes sparse relu'd z row).
// 16-bit radix bisection on LDS ushort keys; exact 32-bit tie-break on the
// few boundary candidates (lowest-index-first, matching lax.top_k).
// Emits compact (idx, val) lists for the sparse decoder.
// ---------------------------------------------------------------------------
__device__ __forceinline__ unsigned sortkey(float f) {
    unsigned u = __float_as_uint(f);
    return (u & 0x80000000u) ? ~u : (u | 0x80000000u);
}

__device__ __forceinline__ int wave_red_int(int v) {
#pragma unroll
    for (int o = 32; o > 0; o >>= 1) v += __shfl_xor(v, o);
    return v;
}

__global__ __launch_bounds__(256) void topk_kernel(float* __restrict__ z,
                                                   int* __restrict__ oIdx,
                                                   float* __restrict__ oVal) {
    __shared__ unsigned short k16[N_DIM];   // 32 KB
    __shared__ int s4[4];
    __shared__ int s_candN;
    __shared__ int s_candIdx[256];
    __shared__ unsigned s_candKey[256];
    __shared__ int s_quota;
    __shared__ int s_outPos;

    const int row = blockIdx.x;
    const int t = threadIdx.x;
    float* zr = z + (size_t)row * N_DIM;

    if (t == 0) { s_candN = 0; s_outPos = 0; }

    // Pass 1: build 16-bit keys in LDS
    for (int i = t; i < N_DIM; i += 256) {
        k16[i] = (unsigned short)(sortkey(zr[i]) >> 16);
    }
    __syncthreads();

    // Bisection: cur = largest 16-bit m with count(k16 >= m) >= 128
    unsigned cur = 0;
    for (int bit = 15; bit >= 0; --bit) {
        unsigned cand = cur | (1u << bit);
        int c = 0;
        for (int i = t; i < N_DIM; i += 256) c += (k16[i] >= cand) ? 1 : 0;
        c = wave_red_int(c);
        __syncthreads();                 // protect s4 from previous iter reads
        if ((t & 63) == 0) s4[t >> 6] = c;
        __syncthreads();
        int total = s4[0] + s4[1] + s4[2] + s4[3];
        if (total >= TOPK) cur = cand;
    }

    // count strictly greater than cur (16-bit)
    {
        int c = 0;
        for (int i = t; i < N_DIM; i += 256) c += (k16[i] > cur) ? 1 : 0;
        c = wave_red_int(c);
        __syncthreads();
        if ((t & 63) == 0) s4[t >> 6] = c;
        __syncthreads();
        int cgt = s4[0] + s4[1] + s4[2] + s4[3];
        if (t == 0) s_quota = TOPK - cgt;
    }
    __syncthreads();

    // Pass 2: collect boundary candidates (k16 == cur), full 32-bit keys
    for (int i = t; i < N_DIM; i += 256) {
        if (k16[i] == (unsigned short)cur) {
            int p = atomicAdd(&s_candN, 1);
            if (p < 256) {
                s_candIdx[p] = i;
                s_candKey[p] = sortkey(zr[i]);
            }
        }
    }
    __syncthreads();

    // Thread 0: partial selection sort -> first `quota` entries are chosen
    // (key desc, index asc on ties — matches lax.top_k tie-break)
    if (t == 0) {
        int n = s_candN < 256 ? s_candN : 256;
        int q = s_quota;
        if (q > n) q = n;   // safety (cannot happen mathematically)
        s_quota = q;
        for (int a = 0; a < q; ++a) {
            int best = a;
            for (int b = a + 1; b < n; ++b) {
                if (s_candKey[b] > s_candKey[best] ||
                    (s_candKey[b] == s_candKey[best] && s_candIdx[b] < s_candIdx[best]))
                    best = b;
            }
            if (best != a) {
                unsigned tk = s_candKey[a]; s_candKey[a] = s_candKey[best]; s_candKey[best] = tk;
                int ti = s_candIdx[a]; s_candIdx[a] = s_candIdx[best]; s_candIdx[best] = ti;
            }
        }
    }
    __syncthreads();

    const int quota = s_quota;
    // Pass 3: write z (relu at selected, 0 elsewhere) + compact lists
    for (int i = t; i < N_DIM; i += 256) {
        float f = zr[i];
        unsigned short kk = k16[i];
        bool sel = kk > (unsigned short)cur;
        if (!sel && kk == (unsigned short)cur) {
            for (int j = 0; j < quota; ++j)
                if (s_candIdx[j] == i) { sel = true; break; }
        }
        float zv = sel ? fmaxf(f, 0.f) : 0.f;
        zr[i] = zv;
        if (sel) {
            int p = atomicAdd(&s_outPos, 1);
            oIdx[row * TOPK + p] = i;
            oVal[row * TOPK + p] = zv;
        }
    }
}

// ---------------------------------------------------------------------------
// Sparse decode + fused loss: one block per row.
// x_hat[row,:] = b_dec + sum_i val_i * W_dec[idx_i,:];  loss += sum((xh-x)^2)/8192
// ---------------------------------------------------------------------------
__global__ __launch_bounds__(256) void decode_kernel(const int* __restrict__ idxL,
                                                     const float* __restrict__ valL,
                                                     const float* __restrict__ Wdec,
                                                     const float* __restrict__ bdec,
                                                     const float* __restrict__ x,
                                                     float* __restrict__ xhat,
                                                     float* __restrict__ loss) {
    __shared__ int s_idx[TOPK];
    __shared__ float s_val[TOPK];
    __shared__ float sred[4];

    const int row = blockIdx.x;
    const int t = threadIdx.x;

    if (t < TOPK) {
        s_idx[t] = idxL[row * TOPK + t];
        s_val[t] = valL[row * TOPK + t];
    }
    __syncthreads();

    float acc[12];
#pragma unroll
    for (int e = 0; e < 12; ++e) acc[e] = bdec[t + e * 256];

    for (int i = 0; i < TOPK; ++i) {
        const float v = s_val[i];
        const float* wr = Wdec + (size_t)s_idx[i] * K_DIM;
#pragma unroll
        for (int e = 0; e < 12; ++e)
            acc[e] = fmaf(v, wr[t + e * 256], acc[e]);
    }

    const float* xr = x + (size_t)row * K_DIM;
    float* xo = xhat + (size_t)row * K_DIM;
    float part = 0.f;
#pragma unroll
    for (int e = 0; e < 12; ++e) {
        float d = acc[e] - xr[t + e * 256];
        part = fmaf(d, d, part);
        xo[t + e * 256] = acc[e];
    }

    // block reduce
#pragma unroll
    for (int o = 32; o > 0; o >>= 1) part += __shfl_xor(part, o);
    if ((t & 63) == 0) sred[t >> 6] = part;
    __syncthreads();
    if (t == 0) {
        float total = sred[0] + sred[1] + sred[2] + sred[3];
        atomicAdd(loss, total * (1.0f / 8192.0f));
    }
}

// ---------------------------------------------------------------------------
extern "C" void kernel_launch(void* const* d_in, const int* in_sizes, int n_in,
                              void* d_out, int out_size, void* d_ws, size_t ws_size,
                              hipStream_t stream) {
    const float* x     = (const float*)d_in[0];
    const float* W_enc = (const float*)d_in[1];
    const float* b_enc = (const float*)d_in[2];
    const float* W_dec = (const float*)d_in[3];
    const float* b_dec = (const float*)d_in[4];

    float* out  = (float*)d_out;
    float* loss = out;
    float* xhat = out + 1;
    float* z    = out + 1 + XHAT_ELEMS;   // z section doubles as `pre` scratch

    int*   oIdx = (int*)d_ws;
    float* oVal = (float*)((char*)d_ws + (size_t)B_ROWS * TOPK * sizeof(int));

    hipMemsetAsync(loss, 0, sizeof(float), stream);

    dim3 g1(N_DIM / 128, B_ROWS / 128);
    enc_gemm<<<g1, 256, 0, stream>>>(x, W_enc, b_enc, z);

    topk_kernel<<<B_ROWS, 256, 0, stream>>>(z, oIdx, oVal);

    decode_kernel<<<B_ROWS, 256, 0, stream>>>(oIdx, oVal, W_dec, b_dec, x, xhat, loss);
}

// Round 3
// 1727.746 us; speedup vs baseline: 1.8284x; 1.8284x over previous
//
#include <hip/hip_runtime.h>
#include <hip/hip_bf16.h>

// Problem dims (fixed by setup_inputs)
#define B_ROWS 2048
#define K_DIM  3072     // T*d_in = 4*768
#define N_DIM  16384    // d_sae
#define TOPK   128
#define XHAT_ELEMS (B_ROWS * K_DIM)   // 6291456

typedef __bf16 bf16x8 __attribute__((ext_vector_type(8)));
typedef float  f32x4  __attribute__((ext_vector_type(4)));

#define LDSTRIDE 40   // ushorts per LDS row: 32 data + 8 pad = 80 B (16B-aligned, 2-way banks)

// bf16 round-to-nearest-even, returned as the fp32 bit pattern's high 16 bits
// kept in place (low 16 zeroed). Pure integer math (no HIP class types).
__device__ __forceinline__ unsigned bf16rne(float f) {
    unsigned u = __float_as_uint(f);
    unsigned r = u + 0x7fffu + ((u >> 16) & 1u);
    return r & 0xffff0000u;
}
// pack bf16(x) into low 16, bf16(y) into high 16
__device__ __forceinline__ unsigned pk2_rne(float x, float y) {
    return (bf16rne(x) >> 16) | bf16rne(y);
}
__device__ __forceinline__ float lo16f(unsigned u) { return __uint_as_float(u << 16); }
__device__ __forceinline__ float hi16f(unsigned u) { return __uint_as_float(u & 0xffff0000u); }

// ---------------------------------------------------------------------------
// Encoder GEMM via bf16x2-split MFMA:
//   pre = X * W + b_enc   computed as  Ahi*Bhi + Ahi*Blo + Alo*Bhi
// 128x128 tile, BK=32, 256 threads (4 waves, 64x64 per wave, 16x16x32 MFMA).
// Split fp32 -> (hi,lo) bf16 fused into LDS staging.
// ---------------------------------------------------------------------------
__global__ __launch_bounds__(256) void enc_gemm_mfma(const float* __restrict__ X,
                                                     const float* __restrict__ W,
                                                     const float* __restrict__ benc,
                                                     float* __restrict__ pre) {
    __shared__ unsigned short Ahi[128 * LDSTRIDE], Alo[128 * LDSTRIDE];
    __shared__ unsigned short Bhi[128 * LDSTRIDE], Blo[128 * LDSTRIDE];

    const int t   = threadIdx.x;
    const int bid = blockIdx.x;
    const int mt  = bid & 15;     // M tile fast-varying: consecutive blocks share W strip
    const int nt  = bid >> 4;
    const int m0  = mt * 128, n0 = nt * 128;

    // Staging coordinates
    int am[4], akq[4], bn[4], bkq[4];
    const float* Xp[4];
    const float* Wp[4];
#pragma unroll
    for (int i = 0; i < 4; ++i) {
        int id = t + 256 * i;
        am[i]  = id >> 3;          // A: 8 float4 per 32-float row
        akq[i] = id & 7;
        Xp[i]  = X + (size_t)(m0 + am[i]) * K_DIM + akq[i] * 4;
        bn[i]  = id & 127;         // B: 4 k-strided dwords per (n, kq)
        bkq[i] = id >> 7;
        Wp[i]  = W + (size_t)(bkq[i] * 4) * N_DIM + n0 + bn[i];
    }

    f32x4 acc[4][4];
#pragma unroll
    for (int mi = 0; mi < 4; ++mi)
#pragma unroll
        for (int ni = 0; ni < 4; ++ni) acc[mi][ni] = (f32x4)0.f;

    // Initial prefetch (k0 = 0)
    float4 aR[4];
    float  bR[4][4];
#pragma unroll
    for (int i = 0; i < 4; ++i) {
        aR[i] = *(const float4*)(Xp[i]);
#pragma unroll
        for (int j = 0; j < 4; ++j) bR[i][j] = Wp[i][(size_t)j * N_DIM];
    }

    const int w = t >> 6, lane = t & 63;
    const int wm = (w >> 1) * 64, wn = (w & 1) * 64;
    const int fm = lane & 15, fk = lane >> 4;

    for (int k0 = 0; k0 < K_DIM; k0 += 32) {
        __syncthreads();
        // Split + stage current tile
#pragma unroll
        for (int i = 0; i < 4; ++i) {
            float4 v = aR[i];
            unsigned h0 = pk2_rne(v.x, v.y), h1 = pk2_rne(v.z, v.w);
            unsigned l0 = pk2_rne(v.x - lo16f(h0), v.y - hi16f(h0));
            unsigned l1 = pk2_rne(v.z - lo16f(h1), v.w - hi16f(h1));
            int off = am[i] * LDSTRIDE + akq[i] * 4;
            uint2 uh; uh.x = h0; uh.y = h1;
            uint2 ul; ul.x = l0; ul.y = l1;
            *(uint2*)&Ahi[off] = uh;
            *(uint2*)&Alo[off] = ul;

            float w0 = bR[i][0], w1 = bR[i][1], w2 = bR[i][2], w3 = bR[i][3];
            unsigned g0 = pk2_rne(w0, w1), g1 = pk2_rne(w2, w3);
            unsigned m0u = pk2_rne(w0 - lo16f(g0), w1 - hi16f(g0));
            unsigned m1u = pk2_rne(w2 - lo16f(g1), w3 - hi16f(g1));
            int boff = bn[i] * LDSTRIDE + bkq[i] * 4;
            uint2 gh; gh.x = g0; gh.y = g1;
            uint2 gl; gl.x = m0u; gl.y = m1u;
            *(uint2*)&Bhi[boff] = gh;
            *(uint2*)&Blo[boff] = gl;
        }
        __syncthreads();

        // Prefetch next tile into registers (lands during MFMA compute)
        if (k0 + 32 < K_DIM) {
#pragma unroll
            for (int i = 0; i < 4; ++i) {
                aR[i] = *(const float4*)(Xp[i] + (k0 + 32));
                const float* p = Wp[i] + (size_t)(k0 + 32) * N_DIM;
#pragma unroll
                for (int j = 0; j < 4; ++j) bR[i][j] = p[(size_t)j * N_DIM];
            }
        }

        // Compute: 48 MFMAs (16 tiles x 3 split products)
        bf16x8 aH[4], aL[4];
#pragma unroll
        for (int mi = 0; mi < 4; ++mi) {
            int r = (wm + mi * 16 + fm) * LDSTRIDE + fk * 8;
            aH[mi] = *(const bf16x8*)&Ahi[r];
            aL[mi] = *(const bf16x8*)&Alo[r];
        }
#pragma unroll
        for (int ni = 0; ni < 4; ++ni) {
            int r = (wn + ni * 16 + fm) * LDSTRIDE + fk * 8;
            bf16x8 bH = *(const bf16x8*)&Bhi[r];
            bf16x8 bL = *(const bf16x8*)&Blo[r];
#pragma unroll
            for (int mi = 0; mi < 4; ++mi) {
                acc[mi][ni] = __builtin_amdgcn_mfma_f32_16x16x32_bf16(aH[mi], bH, acc[mi][ni], 0, 0, 0);
                acc[mi][ni] = __builtin_amdgcn_mfma_f32_16x16x32_bf16(aH[mi], bL, acc[mi][ni], 0, 0, 0);
                acc[mi][ni] = __builtin_amdgcn_mfma_f32_16x16x32_bf16(aL[mi], bH, acc[mi][ni], 0, 0, 0);
            }
        }
    }

    // Epilogue: + b_enc, store (C/D layout: col=lane&15, row=(lane>>4)*4+reg)
    const int frow = fk * 4, fcol = fm;
#pragma unroll
    for (int ni = 0; ni < 4; ++ni) {
        int col = n0 + wn + ni * 16 + fcol;
        float bv = benc[col];
#pragma unroll
        for (int mi = 0; mi < 4; ++mi) {
            int row = m0 + wm + mi * 16 + frow;
            float* p = pre + (size_t)row * N_DIM + col;
#pragma unroll
            for (int r = 0; r < 4; ++r) p[(size_t)r * N_DIM] = acc[mi][ni][r] + bv;
        }
    }
}

// ---------------------------------------------------------------------------
// Top-k per row (in place). 16-bit radix bisection on LDS keys; exact 32-bit
// tie-break on boundary candidates (lowest-index-first, matches lax.top_k).
// ---------------------------------------------------------------------------
__device__ __forceinline__ unsigned sortkey(float f) {
    unsigned u = __float_as_uint(f);
    return (u & 0x80000000u) ? ~u : (u | 0x80000000u);
}

__device__ __forceinline__ int wave_red_int(int v) {
#pragma unroll
    for (int o = 32; o > 0; o >>= 1) v += __shfl_xor(v, o);
    return v;
}

__global__ __launch_bounds__(256) void topk_kernel(float* __restrict__ z,
                                                   int* __restrict__ oIdx,
                                                   float* __restrict__ oVal) {
    __shared__ unsigned short k16[N_DIM];   // 32 KB
    __shared__ int s4[4];
    __shared__ int s_candN;
    __shared__ int s_candIdx[256];
    __shared__ unsigned s_candKey[256];
    __shared__ int s_quota;
    __shared__ int s_outPos;

    const int row = blockIdx.x;
    const int t = threadIdx.x;
    float* zr = z + (size_t)row * N_DIM;

    if (t == 0) { s_candN = 0; s_outPos = 0; }

    for (int i = t; i < N_DIM; i += 256) {
        k16[i] = (unsigned short)(sortkey(zr[i]) >> 16);
    }
    __syncthreads();

    unsigned cur = 0;
    for (int bit = 15; bit >= 0; --bit) {
        unsigned cand = cur | (1u << bit);
        int c = 0;
        for (int i = t; i < N_DIM; i += 256) c += (k16[i] >= cand) ? 1 : 0;
        c = wave_red_int(c);
        __syncthreads();
        if ((t & 63) == 0) s4[t >> 6] = c;
        __syncthreads();
        int total = s4[0] + s4[1] + s4[2] + s4[3];
        if (total >= TOPK) cur = cand;
    }

    {
        int c = 0;
        for (int i = t; i < N_DIM; i += 256) c += (k16[i] > cur) ? 1 : 0;
        c = wave_red_int(c);
        __syncthreads();
        if ((t & 63) == 0) s4[t >> 6] = c;
        __syncthreads();
        int cgt = s4[0] + s4[1] + s4[2] + s4[3];
        if (t == 0) s_quota = TOPK - cgt;
    }
    __syncthreads();

    for (int i = t; i < N_DIM; i += 256) {
        if (k16[i] == (unsigned short)cur) {
            int p = atomicAdd(&s_candN, 1);
            if (p < 256) {
                s_candIdx[p] = i;
                s_candKey[p] = sortkey(zr[i]);
            }
        }
    }
    __syncthreads();

    if (t == 0) {
        int n = s_candN < 256 ? s_candN : 256;
        int q = s_quota;
        if (q > n) q = n;
        s_quota = q;
        for (int a = 0; a < q; ++a) {
            int best = a;
            for (int b = a + 1; b < n; ++b) {
                if (s_candKey[b] > s_candKey[best] ||
                    (s_candKey[b] == s_candKey[best] && s_candIdx[b] < s_candIdx[best]))
                    best = b;
            }
            if (best != a) {
                unsigned tk = s_candKey[a]; s_candKey[a] = s_candKey[best]; s_candKey[best] = tk;
                int ti = s_candIdx[a]; s_candIdx[a] = s_candIdx[best]; s_candIdx[best] = ti;
            }
        }
    }
    __syncthreads();

    const int quota = s_quota;
    for (int i = t; i < N_DIM; i += 256) {
        float f = zr[i];
        unsigned short kk = k16[i];
        bool sel = kk > (unsigned short)cur;
        if (!sel && kk == (unsigned short)cur) {
            for (int j = 0; j < quota; ++j)
                if (s_candIdx[j] == i) { sel = true; break; }
        }
        float zv = sel ? fmaxf(f, 0.f) : 0.f;
        zr[i] = zv;
        if (sel) {
            int p = atomicAdd(&s_outPos, 1);
            oIdx[row * TOPK + p] = i;
            oVal[row * TOPK + p] = zv;
        }
    }
}

// ---------------------------------------------------------------------------
// Sparse decode + fused loss: one block per row.
// ---------------------------------------------------------------------------
__global__ __launch_bounds__(256) void decode_kernel(const int* __restrict__ idxL,
                                                     const float* __restrict__ valL,
                                                     const float* __restrict__ Wdec,
                                                     const float* __restrict__ bdec,
                                                     const float* __restrict__ x,
                                                     float* __restrict__ xhat,
                                                     float* __restrict__ loss) {
    __shared__ int s_idx[TOPK];
    __shared__ float s_val[TOPK];
    __shared__ float sred[4];

    const int row = blockIdx.x;
    const int t = threadIdx.x;

    if (t < TOPK) {
        s_idx[t] = idxL[row * TOPK + t];
        s_val[t] = valL[row * TOPK + t];
    }
    __syncthreads();

    float acc[12];
#pragma unroll
    for (int e = 0; e < 12; ++e) acc[e] = bdec[t + e * 256];

    for (int i = 0; i < TOPK; ++i) {
        const float v = s_val[i];
        const float* wr = Wdec + (size_t)s_idx[i] * K_DIM;
#pragma unroll
        for (int e = 0; e < 12; ++e)
            acc[e] = fmaf(v, wr[t + e * 256], acc[e]);
    }

    const float* xr = x + (size_t)row * K_DIM;
    float* xo = xhat + (size_t)row * K_DIM;
    float part = 0.f;
#pragma unroll
    for (int e = 0; e < 12; ++e) {
        float d = acc[e] - xr[t + e * 256];
        part = fmaf(d, d, part);
        xo[t + e * 256] = acc[e];
    }

#pragma unroll
    for (int o = 32; o > 0; o >>= 1) part += __shfl_xor(part, o);
    if ((t & 63) == 0) sred[t >> 6] = part;
    __syncthreads();
    if (t == 0) {
        float total = sred[0] + sred[1] + sred[2] + sred[3];
        atomicAdd(loss, total * (1.0f / 8192.0f));
    }
}

// ---------------------------------------------------------------------------
extern "C" void kernel_launch(void* const* d_in, const int* in_sizes, int n_in,
                              void* d_out, int out_size, void* d_ws, size_t ws_size,
                              hipStream_t stream) {
    const float* x     = (const float*)d_in[0];
    const float* W_enc = (const float*)d_in[1];
    const float* b_enc = (const float*)d_in[2];
    const float* W_dec = (const float*)d_in[3];
    const float* b_dec = (const float*)d_in[4];

    float* out  = (float*)d_out;
    float* loss = out;
    float* xhat = out + 1;
    float* z    = out + 1 + XHAT_ELEMS;   // z section doubles as `pre` scratch

    int*   oIdx = (int*)d_ws;
    float* oVal = (float*)((char*)d_ws + (size_t)B_ROWS * TOPK * sizeof(int));

    (void)hipMemsetAsync(loss, 0, sizeof(float), stream);

    enc_gemm_mfma<<<2048, 256, 0, stream>>>(x, W_enc, b_enc, z);

    topk_kernel<<<B_ROWS, 256, 0, stream>>>(z, oIdx, oVal);

    decode_kernel<<<B_ROWS, 256, 0, stream>>>(oIdx, oVal, W_dec, b_dec, x, xhat, loss);
}